// Round 2
// baseline (6110.173 us; speedup 1.0000x reference)
//
#include <hip/hip_runtime.h>
#include <math.h>

// ============================================================================
// DeformConv fused pipeline, fp32 round-1 (bugfix: cam_use Ft tile load
// covered only half the n-tile — 4 passes instead of 8).
//
// Pipeline per branch i (params shared for z/x of the same branch):
//   1. energy_kernel  : E[b,c,d] = sum_n f[b,c,n] f[b,d,n]       (orig inputs)
//   2. softmax_kernel : attn = exp(min_d E - E) / sum  (== softmax(max-E))
//   3. cam_use_kernel : g[b,n,c] = f[b,c,n] + gamma * sum_d attnX[c,d] f[b,d,n]
//                       (CROSS: z uses x's attn, x uses z's attn; channel-last)
//   4. deform_kernel  : per 64(32)-pixel tile:
//        stage0: 3x3x256 offset conv (18ch) -> py/px in LDS (fused, no HBM)
//        loop c-chunks of 16: bilinear-sample val[144][TP] into LDS
//                             (corner idx/wgt channel-invariant -> float4 rows)
//                             then GEMM vs WT[2304][256], 4o x TP/4pix regs
//   prep_kernel: WT = dw^T (kk-major), offwP[kyx][j][c] for coalesced stage0.
// ============================================================================

#define BB 32

// ---------- prep: transpose weights ----------
__global__ void prep_kernel(const float* __restrict__ dw,
                            const float* __restrict__ offw,
                            float* __restrict__ WT,      // [2304][256]
                            float* __restrict__ offwP) { // [9][18][256]
    int bx = blockIdx.x;
    int t  = threadIdx.x;
    if (bx < 2304) {
        WT[(size_t)bx * 256 + t] = dw[(size_t)t * 2304 + bx];
    } else {
        int r = bx - 2304;            // [0,162): kyx*18 + j
        int kyx = r / 18, j = r % 18;
        offwP[((size_t)(kyx * 18 + j)) * 256 + t] = offw[((size_t)(j * 256 + t)) * 9 + kyx];
    }
}

// ---------- energy: E[b,c,d] = sum_n f[c,n] f[d,n] ----------
__global__ void energy_kernel(const float* __restrict__ f,
                              float* __restrict__ energy, int N) {
    int b  = blockIdx.z;
    int c0 = blockIdx.x * 64;
    int d0 = blockIdx.y * 64;
    int t  = threadIdx.x;
    __shared__ __align__(16) float A[32][68];
    __shared__ __align__(16) float Bs[32][68];
    float acc[4][4] = {};
    int cc0 = (t & 15) * 4;
    int dd0 = (t >> 4) * 4;
    const float* fb = f + (size_t)b * 256 * N;
    for (int n0 = 0; n0 < N; n0 += 32) {
        #pragma unroll
        for (int pass = 0; pass < 8; ++pass) {
            int idx = pass * 256 + t;
            int nn = idx & 31;
            int rr = idx >> 5;        // 0..63
            int n = n0 + nn;
            float va = (n < N) ? fb[(size_t)(c0 + rr) * N + n] : 0.f;
            float vb = (n < N) ? fb[(size_t)(d0 + rr) * N + n] : 0.f;
            A[nn][rr]  = va;
            Bs[nn][rr] = vb;
        }
        __syncthreads();
        #pragma unroll 8
        for (int nn = 0; nn < 32; ++nn) {
            float4 a4 = *(const float4*)&A[nn][cc0];
            float4 b4 = *(const float4*)&Bs[nn][dd0];
            float av[4] = {a4.x, a4.y, a4.z, a4.w};
            float bv[4] = {b4.x, b4.y, b4.z, b4.w};
            #pragma unroll
            for (int i = 0; i < 4; ++i)
                #pragma unroll
                for (int j = 0; j < 4; ++j)
                    acc[i][j] += av[i] * bv[j];
        }
        __syncthreads();
    }
    #pragma unroll
    for (int i = 0; i < 4; ++i) {
        float4 o4 = {acc[i][0], acc[i][1], acc[i][2], acc[i][3]};
        *(float4*)&energy[((size_t)b * 256 + (c0 + cc0 + i)) * 256 + d0 + dd0] = o4;
    }
}

// ---------- softmax over rows: attn = exp(min - e) / sum ----------
__global__ void softmax_kernel(float* __restrict__ attn) {
    int row = blockIdx.x;             // b*256 + c
    int t = threadIdx.x;
    float e = attn[(size_t)row * 256 + t];
    __shared__ float red[256];
    red[t] = e;
    __syncthreads();
    for (int s = 128; s > 0; s >>= 1) {
        if (t < s) red[t] = fminf(red[t], red[t + s]);
        __syncthreads();
    }
    float mn = red[0];
    __syncthreads();
    float p = __expf(mn - e);
    red[t] = p;
    __syncthreads();
    for (int s = 128; s > 0; s >>= 1) {
        if (t < s) red[t] += red[t + s];
        __syncthreads();
    }
    float inv = 1.f / red[0];
    attn[(size_t)row * 256 + t] = p * inv;
}

// ---------- cam_use (cross attn), channel-last output ----------
// g[b][n][c] = f[b][c][n] + gamma * sum_d attn[b][c][d] * f[b][d][n]
__global__ void cam_use_kernel(const float* __restrict__ f,
                               const float* __restrict__ attn,
                               const float* __restrict__ gamma,
                               float* __restrict__ g, int N) {
    int b  = blockIdx.z;
    int n0 = blockIdx.x * 64;
    int c0 = blockIdx.y * 64;
    int t  = threadIdx.x;
    __shared__ __align__(16) float At[32][68];  // [dd][cc] = attn[c0+cc][d0+dd]
    __shared__ __align__(16) float Ft[32][68];  // [dd][nn] = f[d0+dd][n0+nn]
    float acc[4][4] = {};                       // [c][n]
    int cc0 = (t & 15) * 4;
    int nn0 = (t >> 4) * 4;
    const float* fb = f + (size_t)b * 256 * N;
    const float* ab = attn + (size_t)b * 256 * 256;
    for (int d0 = 0; d0 < 256; d0 += 32) {
        #pragma unroll
        for (int pass = 0; pass < 8; ++pass) {
            int idx = pass * 256 + t;
            int dd = idx & 31;
            int cc = idx >> 5;
            At[dd][cc] = ab[(size_t)(c0 + cc) * 256 + d0 + dd];
        }
        // FIX (round 1): full 32x64 tile needs 8 passes (was 4 with nn&31 —
        // upper half of every n-tile read uninitialized LDS).
        #pragma unroll
        for (int pass = 0; pass < 8; ++pass) {
            int idx = pass * 256 + t;
            int nn = idx & 63;
            int dd = idx >> 6;        // 0..31
            int n = n0 + nn;
            Ft[dd][nn] = (n < N) ? fb[(size_t)(d0 + dd) * N + n] : 0.f;
        }
        __syncthreads();
        #pragma unroll 8
        for (int dd = 0; dd < 32; ++dd) {
            float4 a4 = *(const float4*)&At[dd][cc0];
            float4 f4 = *(const float4*)&Ft[dd][nn0];
            float av[4] = {a4.x, a4.y, a4.z, a4.w};
            float fv[4] = {f4.x, f4.y, f4.z, f4.w};
            #pragma unroll
            for (int i = 0; i < 4; ++i)
                #pragma unroll
                for (int j = 0; j < 4; ++j)
                    acc[i][j] += av[i] * fv[j];
        }
        __syncthreads();
    }
    float gam = gamma[0];
    #pragma unroll
    for (int j = 0; j < 4; ++j) {
        int n = n0 + nn0 + j;
        if (n >= N) continue;
        float4 o4;
        o4.x = fb[(size_t)(c0 + cc0 + 0) * N + n] + gam * acc[0][j];
        o4.y = fb[(size_t)(c0 + cc0 + 1) * N + n] + gam * acc[1][j];
        o4.z = fb[(size_t)(c0 + cc0 + 2) * N + n] + gam * acc[2][j];
        o4.w = fb[(size_t)(c0 + cc0 + 3) * N + n] + gam * acc[3][j];
        *(float4*)&g[((size_t)b * N + n) * 256 + c0 + cc0] = o4;
    }
}

// ---------- fused offset-conv + bilinear sample + deform GEMM ----------
template<int TP>
__global__ void deform_kernel(const float* __restrict__ g,      // [B][N][256]
                              const float* __restrict__ WT,     // [2304][256]
                              const float* __restrict__ offwP,  // [9][18][256]
                              const float* __restrict__ offb,   // [18]
                              float* __restrict__ out,          // [B][256][N]
                              int H, int W) {
    const int N = H * W;
    const int b  = blockIdx.y;
    const int p0 = blockIdx.x * TP;
    const int t  = threadIdx.x;
    constexpr int PARTS = 256 / TP;      // 4 (TP=64) or 8 (TP=32)
    constexpr int CPART = 256 / PARTS;   // 64 or 32
    constexpr int KCH = 16 * 9;          // 144 kk per 16-channel chunk
    constexpr int PB = TP / 4;           // pixels per thread in GEMM

    __shared__ __align__(16) float pyx[TP][9][2];
    struct __align__(16) SM {
        union {
            float part[TP][PARTS][18];
            float val[KCH][TP + 4];
            float outs[128][TP + 1];
        };
    };
    __shared__ SM sm;

    const float* gb = g + (size_t)b * N * 256;

    // ---- stage 0: offset conv (18 ch) for this pixel tile ----
    {
        int pixl = t / PARTS;
        int part = t % PARTS;
        int pix = p0 + pixl;
        float a0[18];
        #pragma unroll
        for (int j = 0; j < 18; ++j) a0[j] = 0.f;
        if (pix < N) {
            int h = pix / W, w = pix % W;
            for (int kyx = 0; kyx < 9; ++kyx) {
                int y = h + kyx / 3 - 1;
                int x = w + kyx % 3 - 1;
                if (y < 0 || y >= H || x < 0 || x >= W) continue;
                const float* grow = gb + (size_t)(y * W + x) * 256 + part * CPART;
                const float* wrow = offwP + (size_t)kyx * 18 * 256 + part * CPART;
                for (int c4 = 0; c4 < CPART; c4 += 4) {
                    float4 g4 = *(const float4*)(grow + c4);
                    #pragma unroll
                    for (int j = 0; j < 18; ++j) {
                        float4 w4 = *(const float4*)(wrow + (size_t)j * 256 + c4);
                        a0[j] += g4.x * w4.x + g4.y * w4.y + g4.z * w4.z + g4.w * w4.w;
                    }
                }
            }
        }
        #pragma unroll
        for (int j = 0; j < 18; ++j) sm.part[pixl][part][j] = a0[j];
    }
    __syncthreads();
    for (int idx = t; idx < TP * 18; idx += 256) {
        int pixl = idx / 18, j = idx % 18;
        float s = 0.f;
        #pragma unroll
        for (int p = 0; p < PARTS; ++p) s += sm.part[pixl][p][j];
        s += offb[j];
        int pix = p0 + pixl;
        int k = j >> 1, comp = j & 1;
        float base = 0.f;
        if (pix < N) {
            int h = pix / W, w = pix % W;
            base = comp ? (float)(w + (k % 3) - 1) : (float)(h + (k / 3) - 1);
        } else {
            s = 0.f;
        }
        pyx[pixl][k][comp] = base + s;
    }

    // ---- main loop: build sampled val tile per 16-ch chunk, GEMM ----
    float acc[4][PB] = {};
    const int o4  = (t & 63) * 4;
    const int pxb = (t >> 6) * PB;

    for (int c0 = 0; c0 < 256; c0 += 16) {
        __syncthreads();
        for (int pair = t; pair < TP * 9; pair += 256) {
            int pixl = pair / 9;
            int k = pair % 9;
            float py = pyx[pixl][k][0];
            float px = pyx[pixl][k][1];
            float y0f = floorf(py), x0f = floorf(px);
            float fy = py - y0f, fx = px - x0f;
            bool vy0 = (y0f >= 0.f) && (y0f <= (float)(H - 1));
            bool vy1 = (y0f + 1.f >= 0.f) && (y0f + 1.f <= (float)(H - 1));
            bool vx0 = (x0f >= 0.f) && (x0f <= (float)(W - 1));
            bool vx1 = (x0f + 1.f >= 0.f) && (x0f + 1.f <= (float)(W - 1));
            int iy0 = min(max((int)y0f, 0), H - 1);
            int iy1 = min(max((int)y0f + 1, 0), H - 1);
            int ix0 = min(max((int)x0f, 0), W - 1);
            int ix1 = min(max((int)x0f + 1, 0), W - 1);
            float w00 = (vy0 && vx0) ? (1.f - fy) * (1.f - fx) : 0.f;
            float w01 = (vy0 && vx1) ? (1.f - fy) * fx : 0.f;
            float w10 = (vy1 && vx0) ? fy * (1.f - fx) : 0.f;
            float w11 = (vy1 && vx1) ? fy * fx : 0.f;
            const float* r00 = gb + (size_t)(iy0 * W + ix0) * 256 + c0;
            const float* r01 = gb + (size_t)(iy0 * W + ix1) * 256 + c0;
            const float* r10 = gb + (size_t)(iy1 * W + ix0) * 256 + c0;
            const float* r11 = gb + (size_t)(iy1 * W + ix1) * 256 + c0;
            #pragma unroll
            for (int cl = 0; cl < 16; cl += 4) {
                float4 a  = *(const float4*)(r00 + cl);
                float4 bq = *(const float4*)(r01 + cl);
                float4 cq = *(const float4*)(r10 + cl);
                float4 dq = *(const float4*)(r11 + cl);
                sm.val[(cl + 0) * 9 + k][pixl] = w00 * a.x + w01 * bq.x + w10 * cq.x + w11 * dq.x;
                sm.val[(cl + 1) * 9 + k][pixl] = w00 * a.y + w01 * bq.y + w10 * cq.y + w11 * dq.y;
                sm.val[(cl + 2) * 9 + k][pixl] = w00 * a.z + w01 * bq.z + w10 * cq.z + w11 * dq.z;
                sm.val[(cl + 3) * 9 + k][pixl] = w00 * a.w + w01 * bq.w + w10 * cq.w + w11 * dq.w;
            }
        }
        __syncthreads();
        const float* wtc = WT + (size_t)(c0 * 9) * 256;
        for (int kk = 0; kk < KCH; ++kk) {
            float4 wv = *(const float4*)(wtc + (size_t)kk * 256 + o4);
            float wvv[4] = {wv.x, wv.y, wv.z, wv.w};
            #pragma unroll
            for (int p4 = 0; p4 < PB; p4 += 4) {
                float4 v = *(const float4*)&sm.val[kk][pxb + p4];
                float vv[4] = {v.x, v.y, v.z, v.w};
                #pragma unroll
                for (int i = 0; i < 4; ++i)
                    #pragma unroll
                    for (int q = 0; q < 4; ++q)
                        acc[i][p4 + q] += wvv[i] * vv[q];
            }
        }
    }

    // ---- epilogue: LDS transpose then coalesced store ----
    float* ob = out + (size_t)b * 256 * N;
    #pragma unroll
    for (int half = 0; half < 2; ++half) {
        __syncthreads();
        if ((o4 >> 7) == half) {
            int olocal = o4 & 127;
            #pragma unroll
            for (int i = 0; i < 4; ++i)
                #pragma unroll
                for (int p = 0; p < PB; ++p)
                    sm.outs[olocal + i][pxb + p] = acc[i][p];
        }
        __syncthreads();
        for (int idx = t; idx < 128 * TP; idx += 256) {
            int pixl = idx % TP;
            int ol = idx / TP;
            int pix = p0 + pixl;
            if (pix < N)
                ob[(size_t)(half * 128 + ol) * N + pix] = sm.outs[ol][pixl];
        }
    }
}

extern "C" void kernel_launch(void* const* d_in, const int* in_sizes, int n_in,
                              void* d_out, int out_size, void* d_ws, size_t ws_size,
                              hipStream_t stream) {
    const int Nz = 225, Nx = 961;
    const size_t ZSZ = (size_t)BB * 256 * Nz;   // 1,843,200
    const size_t XSZ = (size_t)BB * 256 * Nx;   // 7,872,512

    // Input ordering: setup_inputs dict order (z0,x0,offw0,offb0,dw0,gamma0,...)
    // vs reference signature order (z0,z1,z2,x0,x1,x2,offw0,offb0,dw0,gamma0,...)
    bool dict_order = (in_sizes[1] == (int)XSZ);
    const float *z[3], *x[3], *offw[3], *offb[3], *dw[3], *gamma[3];
    for (int i = 0; i < 3; ++i) {
        if (dict_order) {
            z[i]     = (const float*)d_in[i * 6 + 0];
            x[i]     = (const float*)d_in[i * 6 + 1];
            offw[i]  = (const float*)d_in[i * 6 + 2];
            offb[i]  = (const float*)d_in[i * 6 + 3];
            dw[i]    = (const float*)d_in[i * 6 + 4];
            gamma[i] = (const float*)d_in[i * 6 + 5];
        } else {
            z[i]     = (const float*)d_in[i];
            x[i]     = (const float*)d_in[3 + i];
            offw[i]  = (const float*)d_in[6 + i * 4 + 0];
            offb[i]  = (const float*)d_in[6 + i * 4 + 1];
            dw[i]    = (const float*)d_in[6 + i * 4 + 2];
            gamma[i] = (const float*)d_in[6 + i * 4 + 3];
        }
    }

    float* ws = (float*)d_ws;
    float* WT3    = ws;                       // 3 * 589824
    float* offwP3 = WT3 + 3 * 589824;         // 3 * 41472
    float* attn_z = offwP3 + 3 * 41472;       // 2097152
    float* attn_x = attn_z + 2097152;         // 2097152
    float* gz     = attn_x + 2097152;         // 1843200
    float* gx     = gz + 1843200;             // 7872512
    // total 15,803,904 floats = 63.2 MB

    for (int i = 0; i < 3; ++i)
        prep_kernel<<<2466, 256, 0, stream>>>(dw[i], offw[i],
                                              WT3 + (size_t)i * 589824,
                                              offwP3 + (size_t)i * 41472);

    float* out_f = (float*)d_out;
    for (int i = 0; i < 3; ++i) {
        // attention from ORIGINAL inputs
        energy_kernel<<<dim3(4, 4, BB), 256, 0, stream>>>(z[i], attn_z, Nz);
        energy_kernel<<<dim3(4, 4, BB), 256, 0, stream>>>(x[i], attn_x, Nx);
        softmax_kernel<<<BB * 256, 256, 0, stream>>>(attn_z);
        softmax_kernel<<<BB * 256, 256, 0, stream>>>(attn_x);
        // cross cam_use -> channel-last g
        cam_use_kernel<<<dim3(4, 4, BB), 256, 0, stream>>>(z[i], attn_x, gamma[i], gz, Nz);
        cam_use_kernel<<<dim3(16, 4, BB), 256, 0, stream>>>(x[i], attn_z, gamma[i], gx, Nx);
        // fused offset-conv + deform-sample + GEMM
        float* oz = out_f + (size_t)i * ZSZ;
        float* ox = out_f + 3 * ZSZ + (size_t)i * XSZ;
        deform_kernel<32><<<dim3(8, BB), 256, 0, stream>>>(
            gz, WT3 + (size_t)i * 589824, offwP3 + (size_t)i * 41472, offb[i], oz, 15, 15);
        deform_kernel<64><<<dim3(16, BB), 256, 0, stream>>>(
            gx, WT3 + (size_t)i * 589824, offwP3 + (size_t)i * 41472, offb[i], ox, 31, 31);
    }
}

// Round 3
// 2823.757 us; speedup vs baseline: 2.1638x; 2.1638x over previous
//
#include <hip/hip_runtime.h>
#include <math.h>

// ============================================================================
// Round 2: deform path on f16 MFMA.
//   - offset_kernel: standalone fp32 3x3x256->18 conv (scalar weight loads),
//     writes absolute sample positions pyx[b][pix][18].
//   - deform_mfma_kernel: per 64-px tile: bilinear-sample val->f16 LDS
//     fragments, GEMM vs pre-swizzled f16 weight fragments via
//     mfma_f32_16x16x32_f16. Block tile 256o x 64px, wave = 64o x 64px.
//   - energy/softmax/cam_use unchanged (fp32, round-3 target).
// ============================================================================

#define BB 32

typedef _Float16 f16x8 __attribute__((ext_vector_type(8)));
typedef float    f32x4 __attribute__((ext_vector_type(4)));

// ---------- prep: weight fragment swizzle + offset-weight transpose ----------
// WTs fragment order: for ks in [0,72), ot in [0,16), lane in [0,64), j in [0,8):
//   WTs[((ks*16+ot)*64+lane)*8+j] = f16( dw[o=ot*16+(lane&15)][kk=ks*32+(lane>>4)*8+j] )
__global__ void prep_kernel(const float* __restrict__ dw,
                            const float* __restrict__ offw,
                            _Float16* __restrict__ WTs,   // [589824]
                            float* __restrict__ offwP) {  // [9][18][256]
    int bx = blockIdx.x;
    int t  = threadIdx.x;
    if (bx < 2304) {
        int idx = bx * 256 + t;
        int j    = idx & 7;
        int lane = (idx >> 3) & 63;
        int ot   = (idx >> 9) & 15;
        int ks   = idx >> 13;
        int o  = ot * 16 + (lane & 15);
        int kk = ks * 32 + (lane >> 4) * 8 + j;
        WTs[idx] = (_Float16)dw[(size_t)o * 2304 + kk];
    } else {
        int r = bx - 2304;            // [0,162): kyx*18 + j
        int kyx = r / 18, j = r % 18;
        offwP[((size_t)(kyx * 18 + j)) * 256 + t] = offw[((size_t)(j * 256 + t)) * 9 + kyx];
    }
}

// ---------- energy: E[b,c,d] = sum_n f[c,n] f[d,n] ----------
__global__ void energy_kernel(const float* __restrict__ f,
                              float* __restrict__ energy, int N) {
    int b  = blockIdx.z;
    int c0 = blockIdx.x * 64;
    int d0 = blockIdx.y * 64;
    int t  = threadIdx.x;
    __shared__ __align__(16) float A[32][68];
    __shared__ __align__(16) float Bs[32][68];
    float acc[4][4] = {};
    int cc0 = (t & 15) * 4;
    int dd0 = (t >> 4) * 4;
    const float* fb = f + (size_t)b * 256 * N;
    for (int n0 = 0; n0 < N; n0 += 32) {
        #pragma unroll
        for (int pass = 0; pass < 8; ++pass) {
            int idx = pass * 256 + t;
            int nn = idx & 31;
            int rr = idx >> 5;
            int n = n0 + nn;
            float va = (n < N) ? fb[(size_t)(c0 + rr) * N + n] : 0.f;
            float vb = (n < N) ? fb[(size_t)(d0 + rr) * N + n] : 0.f;
            A[nn][rr]  = va;
            Bs[nn][rr] = vb;
        }
        __syncthreads();
        #pragma unroll 8
        for (int nn = 0; nn < 32; ++nn) {
            float4 a4 = *(const float4*)&A[nn][cc0];
            float4 b4 = *(const float4*)&Bs[nn][dd0];
            float av[4] = {a4.x, a4.y, a4.z, a4.w};
            float bv[4] = {b4.x, b4.y, b4.z, b4.w};
            #pragma unroll
            for (int i = 0; i < 4; ++i)
                #pragma unroll
                for (int j = 0; j < 4; ++j)
                    acc[i][j] += av[i] * bv[j];
        }
        __syncthreads();
    }
    #pragma unroll
    for (int i = 0; i < 4; ++i) {
        float4 o4 = {acc[i][0], acc[i][1], acc[i][2], acc[i][3]};
        *(float4*)&energy[((size_t)b * 256 + (c0 + cc0 + i)) * 256 + d0 + dd0] = o4;
    }
}

// ---------- softmax over rows: attn = exp(min - e) / sum ----------
__global__ void softmax_kernel(float* __restrict__ attn) {
    int row = blockIdx.x;
    int t = threadIdx.x;
    float e = attn[(size_t)row * 256 + t];
    __shared__ float red[256];
    red[t] = e;
    __syncthreads();
    for (int s = 128; s > 0; s >>= 1) {
        if (t < s) red[t] = fminf(red[t], red[t + s]);
        __syncthreads();
    }
    float mn = red[0];
    __syncthreads();
    float p = __expf(mn - e);
    red[t] = p;
    __syncthreads();
    for (int s = 128; s > 0; s >>= 1) {
        if (t < s) red[t] += red[t + s];
        __syncthreads();
    }
    float inv = 1.f / red[0];
    attn[(size_t)row * 256 + t] = p * inv;
}

// ---------- cam_use (cross attn), channel-last output ----------
__global__ void cam_use_kernel(const float* __restrict__ f,
                               const float* __restrict__ attn,
                               const float* __restrict__ gamma,
                               float* __restrict__ g, int N) {
    int b  = blockIdx.z;
    int n0 = blockIdx.x * 64;
    int c0 = blockIdx.y * 64;
    int t  = threadIdx.x;
    __shared__ __align__(16) float At[32][68];
    __shared__ __align__(16) float Ft[32][68];
    float acc[4][4] = {};
    int cc0 = (t & 15) * 4;
    int nn0 = (t >> 4) * 4;
    const float* fb = f + (size_t)b * 256 * N;
    const float* ab = attn + (size_t)b * 256 * 256;
    for (int d0 = 0; d0 < 256; d0 += 32) {
        #pragma unroll
        for (int pass = 0; pass < 8; ++pass) {
            int idx = pass * 256 + t;
            int dd = idx & 31;
            int cc = idx >> 5;
            At[dd][cc] = ab[(size_t)(c0 + cc) * 256 + d0 + dd];
        }
        #pragma unroll
        for (int pass = 0; pass < 8; ++pass) {
            int idx = pass * 256 + t;
            int nn = idx & 63;
            int dd = idx >> 6;
            int n = n0 + nn;
            Ft[dd][nn] = (n < N) ? fb[(size_t)(d0 + dd) * N + n] : 0.f;
        }
        __syncthreads();
        #pragma unroll 8
        for (int dd = 0; dd < 32; ++dd) {
            float4 a4 = *(const float4*)&At[dd][cc0];
            float4 f4 = *(const float4*)&Ft[dd][nn0];
            float av[4] = {a4.x, a4.y, a4.z, a4.w};
            float fv[4] = {f4.x, f4.y, f4.z, f4.w};
            #pragma unroll
            for (int i = 0; i < 4; ++i)
                #pragma unroll
                for (int j = 0; j < 4; ++j)
                    acc[i][j] += av[i] * fv[j];
        }
        __syncthreads();
    }
    float gam = gamma[0];
    #pragma unroll
    for (int j = 0; j < 4; ++j) {
        int n = n0 + nn0 + j;
        if (n >= N) continue;
        float4 o4;
        o4.x = fb[(size_t)(c0 + cc0 + 0) * N + n] + gam * acc[0][j];
        o4.y = fb[(size_t)(c0 + cc0 + 1) * N + n] + gam * acc[1][j];
        o4.z = fb[(size_t)(c0 + cc0 + 2) * N + n] + gam * acc[2][j];
        o4.w = fb[(size_t)(c0 + cc0 + 3) * N + n] + gam * acc[3][j];
        *(float4*)&g[((size_t)b * N + n) * 256 + c0 + cc0] = o4;
    }
}

// ---------- offset conv: pyx[b][pix][18] = base + conv18(g) ----------
// 4 waves each own a 64-channel slice; weight loads are wave-uniform (scalar).
__global__ void offset_kernel(const float* __restrict__ g,
                              const float* __restrict__ offwP,   // [9][18][256]
                              const float* __restrict__ offb,    // [18]
                              float* __restrict__ pyxg,          // [B][N][18]
                              int H, int W) {
    const int N = H * W;
    const int b  = blockIdx.y;
    const int p0 = blockIdx.x * 64;
    const int t  = threadIdx.x;
    const int pixl = t & 63;
    const int q = __builtin_amdgcn_readfirstlane(t >> 6);  // channel quarter
    const int pix = p0 + pixl;
    float acc[18];
    #pragma unroll
    for (int j = 0; j < 18; ++j) acc[j] = 0.f;
    const float* gb = g + (size_t)b * N * 256;
    if (pix < N) {
        int h = pix / W, w_ = pix % W;
        for (int kyx = 0; kyx < 9; ++kyx) {
            int y = h + kyx / 3 - 1;
            int x = w_ + kyx % 3 - 1;
            if (y < 0 || y >= H || x < 0 || x >= W) continue;
            const float* grow = gb + (size_t)(y * W + x) * 256 + q * 64;
            const float* wrow = offwP + (size_t)kyx * 18 * 256 + q * 64;
            for (int c4 = 0; c4 < 16; ++c4) {
                float4 g4 = *(const float4*)(grow + c4 * 4);
                #pragma unroll
                for (int j = 0; j < 18; ++j) {
                    float4 w4 = *(const float4*)(wrow + (size_t)j * 256 + c4 * 4);
                    acc[j] += g4.x * w4.x + g4.y * w4.y + g4.z * w4.z + g4.w * w4.w;
                }
            }
        }
    }
    __shared__ float red[4][64][18];
    #pragma unroll
    for (int j = 0; j < 18; ++j) red[q][pixl][j] = acc[j];
    __syncthreads();
    for (int idx = t; idx < 64 * 18; idx += 256) {
        int pl = idx / 18, j = idx % 18;
        int pp = p0 + pl;
        if (pp >= N) continue;
        float s = red[0][pl][j] + red[1][pl][j] + red[2][pl][j] + red[3][pl][j] + offb[j];
        int k = j >> 1, comp = j & 1;
        int h = pp / W, w_ = pp % W;
        float base = comp ? (float)(w_ + (k % 3) - 1) : (float)(h + (k / 3) - 1);
        pyxg[((size_t)b * N + pp) * 18 + j] = base + s;
    }
}

// ---------- deform: sample->f16 LDS fragments, MFMA GEMM ----------
__global__ void deform_mfma_kernel(const float* __restrict__ g,     // [B][N][256]
                                   const _Float16* __restrict__ WTs,// frag order
                                   const float* __restrict__ pyxg,  // [B][N][18]
                                   float* __restrict__ out,         // [B][256][N]
                                   int H, int W) {
    const int N  = H * W;
    const int b  = blockIdx.y;
    const int p0 = blockIdx.x * 64;
    const int t  = threadIdx.x;
    const int lane = t & 63;
    const int wv   = t >> 6;

    __shared__ float pyx[64][9][2];                    // 4.6 KB
    __shared__ __align__(16) _Float16 valq[36 * 64 * 8]; // 36 KB; [kk8][pix][8]

    const float* gb = g + (size_t)b * N * 256;

    // load sample positions (invalid pixels -> far outside -> weights 0)
    for (int idx = t; idx < 64 * 18; idx += 256) {
        int pixl = idx / 18, j = idx % 18;
        int pix = p0 + pixl;
        float v = -100.0f;
        if (pix < N) v = pyxg[((size_t)b * N + pix) * 18 + j];
        pyx[pixl][j >> 1][j & 1] = v;
    }

    f32x4 acc[4][4];
    #pragma unroll
    for (int i = 0; i < 4; ++i)
        #pragma unroll
        for (int j = 0; j < 4; ++j)
            acc[i][j] = (f32x4){0.f, 0.f, 0.f, 0.f};

    const float Hm1 = (float)(H - 1), Wm1 = (float)(W - 1);

    for (int cc = 0; cc < 8; ++cc) {          // 32-channel chunks
        __syncthreads();                       // valq free (also covers pyx on cc=0)
        // ---- sample 64px x 9kyx x 32ch -> f16 fragments ----
        for (int pair = t; pair < 576; pair += 256) {
            int pixl = pair / 9;
            int kyx  = pair % 9;
            float py = pyx[pixl][kyx][0];
            float px = pyx[pixl][kyx][1];
            float y0f = floorf(py), x0f = floorf(px);
            float fy = py - y0f, fx = px - x0f;
            bool vy0 = (y0f >= 0.f) && (y0f <= Hm1);
            bool vy1 = (y0f + 1.f >= 0.f) && (y0f + 1.f <= Hm1);
            bool vx0 = (x0f >= 0.f) && (x0f <= Wm1);
            bool vx1 = (x0f + 1.f >= 0.f) && (x0f + 1.f <= Wm1);
            int iy0 = min(max((int)y0f, 0), H - 1);
            int iy1 = min(max((int)y0f + 1, 0), H - 1);
            int ix0 = min(max((int)x0f, 0), W - 1);
            int ix1 = min(max((int)x0f + 1, 0), W - 1);
            float w00 = (vy0 && vx0) ? (1.f - fy) * (1.f - fx) : 0.f;
            float w01 = (vy0 && vx1) ? (1.f - fy) * fx : 0.f;
            float w10 = (vy1 && vx0) ? fy * (1.f - fx) : 0.f;
            float w11 = (vy1 && vx1) ? fy * fx : 0.f;
            const float* r00 = gb + (size_t)(iy0 * W + ix0) * 256 + cc * 32;
            const float* r01 = gb + (size_t)(iy0 * W + ix1) * 256 + cc * 32;
            const float* r10 = gb + (size_t)(iy1 * W + ix0) * 256 + cc * 32;
            const float* r11 = gb + (size_t)(iy1 * W + ix1) * 256 + cc * 32;
            #pragma unroll
            for (int c4 = 0; c4 < 8; ++c4) {
                float4 a  = *(const float4*)(r00 + c4 * 4);
                float4 bq = *(const float4*)(r01 + c4 * 4);
                float4 cq = *(const float4*)(r10 + c4 * 4);
                float4 dq = *(const float4*)(r11 + c4 * 4);
                float v0 = w00 * a.x + w01 * bq.x + w10 * cq.x + w11 * dq.x;
                float v1 = w00 * a.y + w01 * bq.y + w10 * cq.y + w11 * dq.y;
                float v2 = w00 * a.z + w01 * bq.z + w10 * cq.z + w11 * dq.z;
                float v3 = w00 * a.w + w01 * bq.w + w10 * cq.w + w11 * dq.w;
                int k0 = (c4 * 4) * 9 + kyx;   // klocal for cl=c4*4
                valq[((k0) >> 3) * 512 + pixl * 8 + ((k0) & 7)]             = (_Float16)v0;
                valq[((k0 + 9) >> 3) * 512 + pixl * 8 + ((k0 + 9) & 7)]     = (_Float16)v1;
                valq[((k0 + 18) >> 3) * 512 + pixl * 8 + ((k0 + 18) & 7)]   = (_Float16)v2;
                valq[((k0 + 27) >> 3) * 512 + pixl * 8 + ((k0 + 27) & 7)]   = (_Float16)v3;
            }
        }
        __syncthreads();
        // ---- MFMA: 9 K-steps of 32 over this chunk ----
        #pragma unroll 3
        for (int ksl = 0; ksl < 9; ++ksl) {
            int ks = cc * 9 + ksl;
            f16x8 afrag[4], bfrag[4];
            #pragma unroll
            for (int ot = 0; ot < 4; ++ot) {
                size_t off = (((size_t)ks * 16 + (wv * 4 + ot)) * 64 + lane) * 8;
                afrag[ot] = *(const f16x8*)(WTs + off);
            }
            #pragma unroll
            for (int pt = 0; pt < 4; ++pt) {
                int vi = ((ksl * 4 + (lane >> 4)) * 64 + pt * 16 + (lane & 15)) * 8;
                bfrag[pt] = *(const f16x8*)(valq + vi);
            }
            #pragma unroll
            for (int ot = 0; ot < 4; ++ot)
                #pragma unroll
                for (int pt = 0; pt < 4; ++pt)
                    acc[ot][pt] = __builtin_amdgcn_mfma_f32_16x16x32_f16(
                        afrag[ot], bfrag[pt], acc[ot][pt], 0, 0, 0);
        }
    }

    // ---- epilogue: C/D layout col=lane&15 (pix), row=(lane>>4)*4+reg (o) ----
    float* ob = out + (size_t)b * 256 * N;
    const int pcol = lane & 15;
    const int quad = lane >> 4;
    #pragma unroll
    for (int pt = 0; pt < 4; ++pt) {
        int pix = p0 + pt * 16 + pcol;
        if (pix >= N) continue;
        #pragma unroll
        for (int ot = 0; ot < 4; ++ot) {
            int o = wv * 64 + ot * 16 + quad * 4;
            #pragma unroll
            for (int r = 0; r < 4; ++r)
                ob[(size_t)(o + r) * N + pix] = acc[ot][pt][r];
        }
    }
}

extern "C" void kernel_launch(void* const* d_in, const int* in_sizes, int n_in,
                              void* d_out, int out_size, void* d_ws, size_t ws_size,
                              hipStream_t stream) {
    const int Nz = 225, Nx = 961;
    const size_t ZSZ = (size_t)BB * 256 * Nz;
    const size_t XSZ = (size_t)BB * 256 * Nx;

    bool dict_order = (in_sizes[1] == (int)XSZ);
    const float *z[3], *x[3], *offw[3], *offb[3], *dw[3], *gamma[3];
    for (int i = 0; i < 3; ++i) {
        if (dict_order) {
            z[i]     = (const float*)d_in[i * 6 + 0];
            x[i]     = (const float*)d_in[i * 6 + 1];
            offw[i]  = (const float*)d_in[i * 6 + 2];
            offb[i]  = (const float*)d_in[i * 6 + 3];
            dw[i]    = (const float*)d_in[i * 6 + 4];
            gamma[i] = (const float*)d_in[i * 6 + 5];
        } else {
            z[i]     = (const float*)d_in[i];
            x[i]     = (const float*)d_in[3 + i];
            offw[i]  = (const float*)d_in[6 + i * 4 + 0];
            offb[i]  = (const float*)d_in[6 + i * 4 + 1];
            dw[i]    = (const float*)d_in[6 + i * 4 + 2];
            gamma[i] = (const float*)d_in[6 + i * 4 + 3];
        }
    }

    // workspace layout (floats)
    float* ws = (float*)d_ws;
    _Float16* WTs3 = (_Float16*)ws;          // 3*589824 f16 = 884736 floats
    float* offwP3 = ws + 884736;             // 3*41472
    float* attn_z = offwP3 + 3 * 41472;      // 2097152
    float* attn_x = attn_z + 2097152;        // 2097152
    float* gz     = attn_x + 2097152;        // 1843200
    float* gx     = gz + 1843200;            // 7872512
    float* pyz    = gx + 7872512;            // 32*225*18 = 129600
    float* pyxx   = pyz + 129600;            // 32*961*18 = 553536
    // total 15,602,304 floats = 62.4 MB

    for (int i = 0; i < 3; ++i)
        prep_kernel<<<2466, 256, 0, stream>>>(dw[i], offw[i],
                                              WTs3 + (size_t)i * 589824,
                                              offwP3 + (size_t)i * 41472);

    float* out_f = (float*)d_out;
    for (int i = 0; i < 3; ++i) {
        energy_kernel<<<dim3(4, 4, BB), 256, 0, stream>>>(z[i], attn_z, Nz);
        energy_kernel<<<dim3(4, 4, BB), 256, 0, stream>>>(x[i], attn_x, Nx);
        softmax_kernel<<<BB * 256, 256, 0, stream>>>(attn_z);
        softmax_kernel<<<BB * 256, 256, 0, stream>>>(attn_x);
        cam_use_kernel<<<dim3(4, 4, BB), 256, 0, stream>>>(z[i], attn_x, gamma[i], gz, Nz);
        cam_use_kernel<<<dim3(16, 4, BB), 256, 0, stream>>>(x[i], attn_z, gamma[i], gx, Nx);

        offset_kernel<<<dim3(4, BB), 256, 0, stream>>>(gz, offwP3 + (size_t)i * 41472,
                                                       offb[i], pyz, 15, 15);
        offset_kernel<<<dim3(16, BB), 256, 0, stream>>>(gx, offwP3 + (size_t)i * 41472,
                                                        offb[i], pyxx, 31, 31);

        float* oz = out_f + (size_t)i * ZSZ;
        float* ox = out_f + 3 * ZSZ + (size_t)i * XSZ;
        deform_mfma_kernel<<<dim3(4, BB), 256, 0, stream>>>(
            gz, WTs3 + (size_t)i * 589824, pyz, oz, 15, 15);
        deform_mfma_kernel<<<dim3(16, BB), 256, 0, stream>>>(
            gx, WTs3 + (size_t)i * 589824, pyxx, ox, 31, 31);
    }
}